// Round 5
// baseline (4186.345 us; speedup 1.0000x reference)
//
#include <hip/hip_runtime.h>
#include <cstdint>

// LSTM LM: logits = LSTM(E[idx] @ Wi) @ Wo + bo
// B=16, S=256, D=256, H=512, 4H=2048, V=50257 (padded to 50304 = 393*128)
//
// Round-5 structure: fused k23 with CU isolation.
//  - static LDS 96 KB -> 1 block/CU; grid = 256 blocks = 256 CUs, all resident.
//  - blocks 0..63   : producers (round-2/4 validated 1-wave recurrence), each
//    ALONE on its CU (round-4 post-mortem: co-resident consumer waves starved
//    the latency-critical sync chain).
//  - blocks 64..255 : 192 consumers; s0-outer / v-inner over 2-3 vocab tiles;
//    `out` written with NON-TEMPORAL stores so the 823 MB stream does not
//    evict WoTP from L2/MALL (round-4: FETCH 1.75 GB = MALL thrash).

typedef __attribute__((ext_vector_type(8))) short short8;
typedef __attribute__((ext_vector_type(4))) float f32x4;
typedef __attribute__((ext_vector_type(4))) unsigned int u32x4;
typedef __attribute__((ext_vector_type(4))) unsigned short ush4;

#define DEVFN static __device__ __forceinline__

DEVFN unsigned short f2bf(float f) {
    unsigned int u = __float_as_uint(f);
    return (unsigned short)((u + 0x7FFFu + ((u >> 16) & 1u)) >> 16);  // RNE
}
DEVFN float bf2f(unsigned short h) { return __uint_as_float(((unsigned int)h) << 16); }
DEVFN float sigm(float x) { return 1.0f / (1.0f + __expf(-x)); }
DEVFN float tanh_fast(float x) {
    float e = __expf(-2.0f * fabsf(x));
    float t = (1.0f - e) / (1.0f + e);
    return copysignf(t, x);
}
DEVFN f32x4 fzero() { f32x4 v = {0.f, 0.f, 0.f, 0.f}; return v; }

// 16B L1+L2-bypass load (sc0 sc1): hsP/flags are written with sc1 stores that
// bypass the (non-coherent, possibly poison-stale) L2s. Result NOT ready until
// s_waitcnt vmcnt(0) + sched_barrier(0) (rule 18).
DEVFN void aload16(u32x4& d, const void* p) {
    asm volatile("global_load_dwordx4 %0, %1, off sc0 sc1" : "=v"(d) : "v"(p));
}

// ---------------- k0: transpose + split Wo -> WoTP[50304][512] packed u32 ----------------
__global__ __launch_bounds__(256) void k0_wot(const float* __restrict__ Wo,
                                              uint32_t* __restrict__ WoTP) {
    __shared__ float tile[32][33];
    const int bx = blockIdx.x;
    const int cb = bx >> 4;          // 0..1571 (vocab tiles)
    const int kb = bx & 15;          // 0..15   (k tiles)
    const int c0 = cb * 32, k0 = kb * 32;
    const int j = threadIdx.x & 31;
    const int i0 = threadIdx.x >> 5; // 0..7
    for (int ii = i0; ii < 32; ii += 8) {
        const int c = c0 + j;
        tile[ii][j] = (c < 50257) ? Wo[(size_t)(k0 + ii) * 50257 + c] : 0.0f;
    }
    __syncthreads();
    for (int ii = i0; ii < 32; ii += 8) {
        const float v = tile[j][ii];  // Wo[k0+j][c0+ii]
        const unsigned short hi = f2bf(v);
        const unsigned short lo = f2bf(v - bf2f(hi));
        WoTP[(size_t)(c0 + ii) * 512 + k0 + j] = (((unsigned int)hi) << 16) | lo;
    }
}

// ---------------- k0b: Wh bf16-lo B-fragments: [wg][nt][q][lane] 16B each ----------------
__global__ __launch_bounds__(256) void k0b_whlo(const float* __restrict__ Wh,
                                                uint32_t* __restrict__ WLO) {
    const int tid = blockIdx.x * 256 + threadIdx.x;   // 0..131071
    const int lane = tid & 63;
    const int q    = (tid >> 6) & 15;
    const int nt   = (tid >> 10) & 1;
    const int wg   = tid >> 11;
    const int cc   = lane & 15;
    const int gcol = (cc >> 2) * 512 + wg * 8 + nt * 4 + (cc & 3);
    const int kbase = q * 32 + (lane >> 4) * 8;
    u32x4 o;
#pragma unroll
    for (int p = 0; p < 4; ++p) {
        unsigned int pair = 0;
#pragma unroll
        for (int e = 0; e < 2; ++e) {
            const int k = kbase + p * 2 + e;
            const float w = Wh[(size_t)k * 2048 + gcol];
            const unsigned short hi = f2bf(w);
            const unsigned short lo = f2bf(w - bf2f(hi));
            pair |= ((unsigned int)lo) << (e * 16);
        }
        o[p] = pair;
    }
    *(u32x4*)(WLO + (size_t)tid * 4) = o;
}

// ---------------- k1: xzH[s][b][g] = bf16( sum_d E[idx[b,s],d] * Wi[d,g] ) ---------------
__global__ __launch_bounds__(256) void k1_xz(const int* __restrict__ idx,
                                             const float* __restrict__ E,
                                             const float* __restrict__ Wi,
                                             unsigned short* __restrict__ xzH) {
    __shared__ float xs[16][256];
    const int s = blockIdx.x;
    const int t = threadIdx.x;
#pragma unroll
    for (int b = 0; b < 16; ++b) {
        const int row = idx[b * 256 + s];
        xs[b][t] = E[(size_t)row * 256 + t];
    }
    __syncthreads();
    for (int half = 0; half < 2; ++half) {
        const int g0 = half * 1024 + t * 4;
        f32x4 acc[16];
#pragma unroll
        for (int b = 0; b < 16; ++b) acc[b] = fzero();
        for (int d = 0; d < 256; ++d) {
            const f32x4 w = *(const f32x4*)&Wi[(size_t)d * 2048 + g0];
#pragma unroll
            for (int b = 0; b < 16; ++b) {
                const float xv = xs[b][d];
                acc[b] += xv * w;
            }
        }
#pragma unroll
        for (int b = 0; b < 16; ++b) {
            ush4 o;
#pragma unroll
            for (int jj = 0; jj < 4; ++jj) o[jj] = f2bf(acc[b][jj]);
            *(ush4*)&xzH[((size_t)s * 16 + b) * 2048 + g0] = o;
        }
    }
}

// ---------------- k23: fused recurrence (producers) + logits GEMM (consumers) ------------
__global__ __launch_bounds__(256, 1) void k23(const float* __restrict__ Wh,
                                              const float* __restrict__ bh,
                                              const unsigned short* __restrict__ xzH,
                                              const short8* __restrict__ WLO8,
                                              uint32_t* __restrict__ hsP,
                                              const uint32_t* __restrict__ zeroh,
                                              uint32_t* __restrict__ flags,
                                              const uint32_t* __restrict__ WoTP,
                                              const float* __restrict__ bo,
                                              float* __restrict__ out) {
    __shared__ __align__(16) char smem[98304];   // 96 KB -> 1 block/CU (isolation)

    if (blockIdx.x < 64) {
        // ================= PRODUCER (round-2/4 validated 1-wave pipeline) =================
        const int wg = blockIdx.x;
        const int tid = threadIdx.x;

        unsigned short* whh = (unsigned short*)smem;   // [32 cols][512 k] bf16-hi, swizzled

        // stage Wh-hi slice with all 256 threads, then waves 1..3 exit
        {
            const int l = tid >> 3, seg = tid & 7;     // l: col 0..31, seg: k segment
            const int cc = l & 15, nt0 = l >> 4;
            const int gcol = (cc >> 2) * 512 + wg * 8 + nt0 * 4 + (cc & 3);
            for (int k8 = seg * 64; k8 < seg * 64 + 64; k8 += 8) {
                short8 v;
#pragma unroll
                for (int i = 0; i < 8; ++i)
                    v[i] = (short)f2bf(Wh[(size_t)(k8 + i) * 2048 + gcol]);
                const int slot = (k8 >> 3) ^ (l & 7);
                *(short8*)((char*)whh + l * 1024 + slot * 16) = v;
            }
        }
        __syncthreads();
        if (tid >= 64) return;

        const int lane = tid;
        const int c = lane & 15;
        const int qtr = lane >> 4;

        int gc[2];
        float bh_v[2];
#pragma unroll
        for (int nt = 0; nt < 2; ++nt) {
            gc[nt] = (c >> 2) * 512 + wg * 8 + nt * 4 + (c & 3);
            bh_v[nt] = bh[gc[nt]];
        }
        float cst[2][4];
#pragma unroll
        for (int nt = 0; nt < 2; ++nt)
#pragma unroll
            for (int r = 0; r < 4; ++r) cst[nt][r] = 0.0f;

        float xzv[2][4];
#pragma unroll
        for (int nt = 0; nt < 2; ++nt)
#pragma unroll
            for (int r = 0; r < 4; ++r)
                xzv[nt][r] = bf2f(xzH[(size_t)(qtr * 4 + r) * 2048 + gc[nt]]);

        const uint32_t* flg = flags + lane;

        for (int t = 0; t < 256; ++t) {
            if (t > 0) {
                while (true) {
                    const uint32_t v = __hip_atomic_load(flg, __ATOMIC_RELAXED,
                                                         __HIP_MEMORY_SCOPE_AGENT);
                    if (__all((int)(v >= (uint32_t)t))) break;
                }
                __builtin_amdgcn_sched_barrier(0);
            }

            const uint32_t* hbase = (t == 0)
                ? (zeroh + (size_t)c * 512)
                : (hsP + ((size_t)(t - 1) * 16 + c) * 512);

            f32x4 acc[2][2];
#pragma unroll
            for (int nt = 0; nt < 2; ++nt) { acc[nt][0] = fzero(); acc[nt][1] = fzero(); }

#pragma unroll
            for (int q = 0; q < 16; ++q) {
                const int kb = q * 32 + qtr * 8;
                const unsigned long long* hb64 = (const unsigned long long*)(hbase + kb);
                unsigned long long d[4];
#pragma unroll
                for (int i = 0; i < 4; ++i)
                    d[i] = __hip_atomic_load(hb64 + i, __ATOMIC_RELAXED,
                                             __HIP_MEMORY_SCOPE_AGENT);
                short8 ahi, alo;
#pragma unroll
                for (int i = 0; i < 4; ++i) {
                    const uint32_t wlo32 = (uint32_t)d[i];
                    const uint32_t whi32 = (uint32_t)(d[i] >> 32);
                    ahi[2 * i]     = (short)(wlo32 >> 16); alo[2 * i]     = (short)(wlo32 & 0xffffu);
                    ahi[2 * i + 1] = (short)(whi32 >> 16); alo[2 * i + 1] = (short)(whi32 & 0xffffu);
                }
#pragma unroll
                for (int nt = 0; nt < 2; ++nt) {
                    const int l = nt * 16 + c;
                    const short8 bhi = *(const short8*)((const char*)whh + l * 1024 +
                                                        (((q * 4 + qtr) ^ (l & 7)) << 4));
                    const short8 blo = WLO8[(((size_t)wg * 2 + nt) * 16 + q) * 64 + lane];
                    f32x4 a = acc[nt][q & 1];
                    a = __builtin_amdgcn_mfma_f32_16x16x32_bf16(ahi, bhi, a, 0, 0, 0);
                    a = __builtin_amdgcn_mfma_f32_16x16x32_bf16(ahi, blo, a, 0, 0, 0);
                    a = __builtin_amdgcn_mfma_f32_16x16x32_bf16(alo, bhi, a, 0, 0, 0);
                    acc[nt][q & 1] = a;
                }
            }

#pragma unroll
            for (int nt = 0; nt < 2; ++nt) {
                f32x4 z4 = acc[nt][0] + acc[nt][1];
#pragma unroll
                for (int r = 0; r < 4; ++r) z4[r] += xzv[nt][r] + bh_v[nt];
#pragma unroll
                for (int r = 0; r < 4; ++r) {
                    const int sb = (lane & 0x33);
                    const float zi = __shfl(z4[r], sb);
                    const float zf = __shfl(z4[r], sb | 4);
                    const float zg = __shfl(z4[r], sb | 8);
                    const float zo = __shfl(z4[r], sb | 12);
                    const float iv = sigm(zi), fv = sigm(zf);
                    const float gv = tanh_fast(zg), ov = sigm(zo);
                    const float cv = fv * cst[nt][r] + iv * gv;
                    cst[nt][r] = cv;
                    const float hv = ov * tanh_fast(cv);
                    if ((c >> 2) == 0) {  // one owner lane per (b, j)
                        const unsigned short hi = f2bf(hv);
                        const unsigned short lo = f2bf(hv - bf2f(hi));
                        const uint32_t packed = (((uint32_t)hi) << 16) | lo;
                        __hip_atomic_store(
                            &hsP[((size_t)t * 16 + qtr * 4 + r) * 512 + wg * 8 + nt * 4 + c],
                            packed, __ATOMIC_RELAXED, __HIP_MEMORY_SCOPE_AGENT);
                    }
                }
            }

            // own h-stores at coherence point before flag becomes visible
            asm volatile("s_waitcnt vmcnt(0)" ::: "memory");
            if (lane == 0)
                __hip_atomic_store(&flags[wg], (uint32_t)(t + 1), __ATOMIC_RELAXED,
                                   __HIP_MEMORY_SCOPE_AGENT);

            if (t < 255) {
#pragma unroll
                for (int nt = 0; nt < 2; ++nt)
#pragma unroll
                    for (int r = 0; r < 4; ++r)
                        xzv[nt][r] = bf2f(xzH[((size_t)(t + 1) * 16 + qtr * 4 + r) * 2048 + gc[nt]]);
            }
        }
    } else {
        // ================= CONSUMER: 192 blocks, s0-outer / v-inner ====================
        unsigned short (*Ah)[64] = (unsigned short(*)[64])(smem);
        unsigned short (*Al)[64] = (unsigned short(*)[64])(smem + 16384);
        unsigned short (*Bh)[64] = (unsigned short(*)[64])(smem + 32768);
        unsigned short (*Bl)[64] = (unsigned short(*)[64])(smem + 49152);

        const int cid = blockIdx.x - 64;   // 0..191
        const int tid = threadIdx.x;
        const int lane = tid & 63;
        const int wv = tid >> 6;
        const int wr = wv >> 1, wc = wv & 1;
        const int srow = tid >> 1, shalf = tid & 1;

        for (int s0 = 0; s0 < 32; ++s0) {
            const unsigned need = (unsigned)(s0 * 8 + 8);
            while (true) {
                const unsigned f = __hip_atomic_load(&flags[lane], __ATOMIC_RELAXED,
                                                     __HIP_MEMORY_SCOPE_AGENT);
                if (__all((int)(f >= need))) break;
                __builtin_amdgcn_s_sleep(32);
            }

            for (int vi = 0; vi < 3; ++vi) {
                const int v = cid + vi * 192;
                if (v >= 393) break;

                f32x4 acc[4][4];
#pragma unroll
                for (int i = 0; i < 4; ++i)
#pragma unroll
                    for (int j = 0; j < 4; ++j) acc[i][j] = fzero();

                for (int kb = 0; kb < 8; ++kb) {
                    __syncthreads();
                    const uint32_t* sa = hsP + (size_t)(s0 * 128 + srow) * 512 + kb * 64 + shalf * 32;
                    const uint32_t* sbp = WoTP + (size_t)(v * 128 + srow) * 512 + kb * 64 + shalf * 32;
                    u32x4 av[8], bv[8];
#pragma unroll
                    for (int g = 0; g < 4; ++g) {
                        aload16(av[2 * g], sa + g * 8);
                        aload16(av[2 * g + 1], sa + g * 8 + 4);
                    }
#pragma unroll
                    for (int g = 0; g < 4; ++g) {
                        bv[2 * g]     = *(const u32x4*)(sbp + g * 8);
                        bv[2 * g + 1] = *(const u32x4*)(sbp + g * 8 + 4);
                    }
                    asm volatile("s_waitcnt vmcnt(0)" ::: "memory");
                    __builtin_amdgcn_sched_barrier(0);
#pragma unroll
                    for (int g = 0; g < 4; ++g) {
                        short8 hi, lo;
#pragma unroll
                        for (int i = 0; i < 4; ++i) {
                            hi[i]     = (short)(av[2 * g][i] >> 16);
                            lo[i]     = (short)(av[2 * g][i] & 0xffffu);
                            hi[4 + i] = (short)(av[2 * g + 1][i] >> 16);
                            lo[4 + i] = (short)(av[2 * g + 1][i] & 0xffffu);
                        }
                        const int sw = ((shalf * 4 + g) ^ (srow & 7)) << 4;
                        *(short8*)((char*)Ah + srow * 128 + sw) = hi;
                        *(short8*)((char*)Al + srow * 128 + sw) = lo;
                    }
#pragma unroll
                    for (int g = 0; g < 4; ++g) {
                        short8 hi, lo;
#pragma unroll
                        for (int i = 0; i < 4; ++i) {
                            hi[i]     = (short)(bv[2 * g][i] >> 16);
                            lo[i]     = (short)(bv[2 * g][i] & 0xffffu);
                            hi[4 + i] = (short)(bv[2 * g + 1][i] >> 16);
                            lo[4 + i] = (short)(bv[2 * g + 1][i] & 0xffffu);
                        }
                        const int sw = ((shalf * 4 + g) ^ (srow & 7)) << 4;
                        *(short8*)((char*)Bh + srow * 128 + sw) = hi;
                        *(short8*)((char*)Bl + srow * 128 + sw) = lo;
                    }
                    __syncthreads();

#pragma unroll
                    for (int q = 0; q < 2; ++q) {
                        short8 afh[4], afl[4], bfh[4], bfl[4];
#pragma unroll
                        for (int mi = 0; mi < 4; ++mi) {
                            const int r = wr * 64 + mi * 16 + (lane & 15);
                            const int sw = ((q * 4 + (lane >> 4)) ^ (r & 7)) << 4;
                            afh[mi] = *(const short8*)((const char*)Ah + r * 128 + sw);
                            afl[mi] = *(const short8*)((const char*)Al + r * 128 + sw);
                        }
#pragma unroll
                        for (int nj = 0; nj < 4; ++nj) {
                            const int r = wc * 64 + nj * 16 + (lane & 15);
                            const int sw = ((q * 4 + (lane >> 4)) ^ (r & 7)) << 4;
                            bfh[nj] = *(const short8*)((const char*)Bh + r * 128 + sw);
                            bfl[nj] = *(const short8*)((const char*)Bl + r * 128 + sw);
                        }
#pragma unroll
                        for (int mi = 0; mi < 4; ++mi)
#pragma unroll
                            for (int nj = 0; nj < 4; ++nj) {
                                f32x4 a = acc[mi][nj];
                                a = __builtin_amdgcn_mfma_f32_16x16x32_bf16(afh[mi], bfh[nj], a, 0, 0, 0);
                                a = __builtin_amdgcn_mfma_f32_16x16x32_bf16(afh[mi], bfl[nj], a, 0, 0, 0);
                                a = __builtin_amdgcn_mfma_f32_16x16x32_bf16(afl[mi], bfh[nj], a, 0, 0, 0);
                                acc[mi][nj] = a;
                            }
                    }
                }

#pragma unroll
                for (int nj = 0; nj < 4; ++nj) {
                    const int colg = v * 128 + wc * 64 + nj * 16 + (lane & 15);
                    if (colg < 50257) {
                        const float bov = bo[colg];
#pragma unroll
                        for (int mi = 0; mi < 4; ++mi)
#pragma unroll
                            for (int r = 0; r < 4; ++r) {
                                const int tr = wr * 64 + mi * 16 + (lane >> 4) * 4 + r;
                                const int ss = s0 * 8 + (tr >> 4);
                                const int bb = tr & 15;
                                // non-temporal: don't let the 823 MB output stream
                                // evict WoTP from L2/MALL
                                __builtin_nontemporal_store(
                                    acc[mi][nj][r] + bov,
                                    &out[((size_t)bb * 256 + ss) * 50257 + colg]);
                            }
                    }
                }
            }
        }
    }
}

// ---------------- launch ----------------------------------------------------------------
// Workspace layout (total ~130 MB <= proven-safe 147 MB):
#define XZH_OFF  0ull           // 256*16*2048*2  = 16,777,216  (bf16 xz)
#define HSP_OFF  16777216ull    // 256*16*512*4   =  8,388,608  (packed u32 h, t-major)
#define ZERO_OFF 25165824ull    // 16*512*4       =     32,768
#define FLG_OFF  25198592ull    // 64*4 = 256
#define WLO_OFF  25198848ull    // 64*2*16*64*16  =  2,097,152
#define WOT_OFF  27296000ull    // 50304*512*4    = 103,022,592

extern "C" void kernel_launch(void* const* d_in, const int* in_sizes, int n_in,
                              void* d_out, int out_size, void* d_ws, size_t ws_size,
                              hipStream_t stream) {
    (void)in_sizes; (void)n_in; (void)out_size; (void)ws_size;
    const int*   idx = (const int*)  d_in[0];
    const float* E   = (const float*)d_in[1];
    const float* Wi  = (const float*)d_in[2];
    const float* Wh  = (const float*)d_in[3];
    const float* bh  = (const float*)d_in[4];
    const float* Wo  = (const float*)d_in[5];
    const float* bo  = (const float*)d_in[6];
    float* out = (float*)d_out;
    char* ws = (char*)d_ws;

    unsigned short* xzH   = (unsigned short*)(ws + XZH_OFF);
    uint32_t*       hsP   = (uint32_t*)      (ws + HSP_OFF);
    uint32_t*       zeroh = (uint32_t*)      (ws + ZERO_OFF);
    uint32_t*       flags = (uint32_t*)      (ws + FLG_OFF);
    uint32_t*       WLO   = (uint32_t*)      (ws + WLO_OFF);
    uint32_t*       WoTP  = (uint32_t*)      (ws + WOT_OFF);

    // zero h(-1) block + flags each call (contiguous region; no cross-replay state)
    hipMemsetAsync(ws + ZERO_OFF, 0, 33024, stream);

    hipLaunchKernelGGL(k0_wot,   dim3(25152), dim3(256), 0, stream, Wo, WoTP);
    hipLaunchKernelGGL(k0b_whlo, dim3(512),   dim3(256), 0, stream, Wh, WLO);
    hipLaunchKernelGGL(k1_xz,    dim3(256),   dim3(256), 0, stream, idx, E, Wi, xzH);
    hipLaunchKernelGGL(k23,      dim3(256),   dim3(256), 0, stream,
                       Wh, bh, xzH, (const short8*)WLO, hsP, zeroh, flags, WoTP, bo, out);
}

// Round 6
// 3829.241 us; speedup vs baseline: 1.0933x; 1.0933x over previous
//
#include <hip/hip_runtime.h>
#include <cstdint>

// LSTM LM: logits = LSTM(E[idx] @ Wi) @ Wo + bo
// B=16, S=256, D=256, H=512, 4H=2048, V=50257 (padded to 50304 = 393*128)
//
// Round-6: round-5 skeleton + MFMA-BURN spin (DPM boost experiment).
//  Evidence: 3 sync protocols x 3 consumer layouts all give 11.5-16 us/step
//  with ~1-6% utilization; critical path arithmetic says ~2 us at 2.4 GHz.
//  => frontier is running at idle clock. Fix: waiting waves burn dummy
//  register-only MFMA between polls to force DPM boost.
//  Also: NT stores reverted to normal cached stores (round-5: NT amplified
//  WRITE 0.9->1.38 GB via uncombined partial-line writes).

typedef __attribute__((ext_vector_type(8))) short short8;
typedef __attribute__((ext_vector_type(4))) float f32x4;
typedef __attribute__((ext_vector_type(4))) unsigned int u32x4;
typedef __attribute__((ext_vector_type(4))) unsigned short ush4;

#define DEVFN static __device__ __forceinline__

DEVFN unsigned short f2bf(float f) {
    unsigned int u = __float_as_uint(f);
    return (unsigned short)((u + 0x7FFFu + ((u >> 16) & 1u)) >> 16);  // RNE
}
DEVFN float bf2f(unsigned short h) { return __uint_as_float(((unsigned int)h) << 16); }
DEVFN float sigm(float x) { return 1.0f / (1.0f + __expf(-x)); }
DEVFN float tanh_fast(float x) {
    float e = __expf(-2.0f * fabsf(x));
    float t = (1.0f - e) / (1.0f + e);
    return copysignf(t, x);
}
DEVFN f32x4 fzero() { f32x4 v = {0.f, 0.f, 0.f, 0.f}; return v; }

// 16B L1+L2-bypass load (sc0 sc1): hsP/flags are written with sc1 stores that
// bypass the (non-coherent, possibly poison-stale) L2s. Result NOT ready until
// s_waitcnt vmcnt(0) + sched_barrier(0) (rule 18).
DEVFN void aload16(u32x4& d, const void* p) {
    asm volatile("global_load_dwordx4 %0, %1, off sc0 sc1" : "=v"(d) : "v"(p));
}

// ---------------- k0: transpose + split Wo -> WoTP[50304][512] packed u32 ----------------
__global__ __launch_bounds__(256) void k0_wot(const float* __restrict__ Wo,
                                              uint32_t* __restrict__ WoTP) {
    __shared__ float tile[32][33];
    const int bx = blockIdx.x;
    const int cb = bx >> 4;          // 0..1571 (vocab tiles)
    const int kb = bx & 15;          // 0..15   (k tiles)
    const int c0 = cb * 32, k0 = kb * 32;
    const int j = threadIdx.x & 31;
    const int i0 = threadIdx.x >> 5; // 0..7
    for (int ii = i0; ii < 32; ii += 8) {
        const int c = c0 + j;
        tile[ii][j] = (c < 50257) ? Wo[(size_t)(k0 + ii) * 50257 + c] : 0.0f;
    }
    __syncthreads();
    for (int ii = i0; ii < 32; ii += 8) {
        const float v = tile[j][ii];  // Wo[k0+j][c0+ii]
        const unsigned short hi = f2bf(v);
        const unsigned short lo = f2bf(v - bf2f(hi));
        WoTP[(size_t)(c0 + ii) * 512 + k0 + j] = (((unsigned int)hi) << 16) | lo;
    }
}

// ---------------- k0b: Wh bf16-lo B-fragments: [wg][nt][q][lane] 16B each ----------------
__global__ __launch_bounds__(256) void k0b_whlo(const float* __restrict__ Wh,
                                                uint32_t* __restrict__ WLO) {
    const int tid = blockIdx.x * 256 + threadIdx.x;   // 0..131071
    const int lane = tid & 63;
    const int q    = (tid >> 6) & 15;
    const int nt   = (tid >> 10) & 1;
    const int wg   = tid >> 11;
    const int cc   = lane & 15;
    const int gcol = (cc >> 2) * 512 + wg * 8 + nt * 4 + (cc & 3);
    const int kbase = q * 32 + (lane >> 4) * 8;
    u32x4 o;
#pragma unroll
    for (int p = 0; p < 4; ++p) {
        unsigned int pair = 0;
#pragma unroll
        for (int e = 0; e < 2; ++e) {
            const int k = kbase + p * 2 + e;
            const float w = Wh[(size_t)k * 2048 + gcol];
            const unsigned short hi = f2bf(w);
            const unsigned short lo = f2bf(w - bf2f(hi));
            pair |= ((unsigned int)lo) << (e * 16);
        }
        o[p] = pair;
    }
    *(u32x4*)(WLO + (size_t)tid * 4) = o;
}

// ---------------- k1: xzH[s][b][g] = bf16( sum_d E[idx[b,s],d] * Wi[d,g] ) ---------------
__global__ __launch_bounds__(256) void k1_xz(const int* __restrict__ idx,
                                             const float* __restrict__ E,
                                             const float* __restrict__ Wi,
                                             unsigned short* __restrict__ xzH) {
    __shared__ float xs[16][256];
    const int s = blockIdx.x;
    const int t = threadIdx.x;
#pragma unroll
    for (int b = 0; b < 16; ++b) {
        const int row = idx[b * 256 + s];
        xs[b][t] = E[(size_t)row * 256 + t];
    }
    __syncthreads();
    for (int half = 0; half < 2; ++half) {
        const int g0 = half * 1024 + t * 4;
        f32x4 acc[16];
#pragma unroll
        for (int b = 0; b < 16; ++b) acc[b] = fzero();
        for (int d = 0; d < 256; ++d) {
            const f32x4 w = *(const f32x4*)&Wi[(size_t)d * 2048 + g0];
#pragma unroll
            for (int b = 0; b < 16; ++b) {
                const float xv = xs[b][d];
                acc[b] += xv * w;
            }
        }
#pragma unroll
        for (int b = 0; b < 16; ++b) {
            ush4 o;
#pragma unroll
            for (int jj = 0; jj < 4; ++jj) o[jj] = f2bf(acc[b][jj]);
            *(ush4*)&xzH[((size_t)s * 16 + b) * 2048 + g0] = o;
        }
    }
}

// ---------------- k23: fused recurrence (producers) + logits GEMM (consumers) ------------
__global__ __launch_bounds__(256, 1) void k23(const float* __restrict__ Wh,
                                              const float* __restrict__ bh,
                                              const unsigned short* __restrict__ xzH,
                                              const short8* __restrict__ WLO8,
                                              uint32_t* __restrict__ hsP,
                                              const uint32_t* __restrict__ zeroh,
                                              uint32_t* __restrict__ flags,
                                              const uint32_t* __restrict__ WoTP,
                                              const float* __restrict__ bo,
                                              float* __restrict__ out) {
    __shared__ __align__(16) char smem[98304];   // 96 KB -> 1 block/CU (isolation)

    if (blockIdx.x < 64) {
        // ================= PRODUCER (validated 1-wave pipeline + burn-poll) ==============
        const int wg = blockIdx.x;
        const int tid = threadIdx.x;

        unsigned short* whh = (unsigned short*)smem;   // [32 cols][512 k] bf16-hi, swizzled

        // stage Wh-hi slice with all 256 threads, then waves 1..3 exit
        {
            const int l = tid >> 3, seg = tid & 7;     // l: col 0..31, seg: k segment
            const int cc = l & 15, nt0 = l >> 4;
            const int gcol = (cc >> 2) * 512 + wg * 8 + nt0 * 4 + (cc & 3);
            for (int k8 = seg * 64; k8 < seg * 64 + 64; k8 += 8) {
                short8 v;
#pragma unroll
                for (int i = 0; i < 8; ++i)
                    v[i] = (short)f2bf(Wh[(size_t)(k8 + i) * 2048 + gcol]);
                const int slot = (k8 >> 3) ^ (l & 7);
                *(short8*)((char*)whh + l * 1024 + slot * 16) = v;
            }
        }
        __syncthreads();
        if (tid >= 64) return;

        const int lane = tid;
        const int c = lane & 15;
        const int qtr = lane >> 4;

        int gc[2];
        float bh_v[2];
#pragma unroll
        for (int nt = 0; nt < 2; ++nt) {
            gc[nt] = (c >> 2) * 512 + wg * 8 + nt * 4 + (c & 3);
            bh_v[nt] = bh[gc[nt]];
        }
        float cst[2][4];
#pragma unroll
        for (int nt = 0; nt < 2; ++nt)
#pragma unroll
            for (int r = 0; r < 4; ++r) cst[nt][r] = 0.0f;

        float xzv[2][4];
#pragma unroll
        for (int nt = 0; nt < 2; ++nt)
#pragma unroll
            for (int r = 0; r < 4; ++r)
                xzv[nt][r] = bf2f(xzH[(size_t)(qtr * 4 + r) * 2048 + gc[nt]]);

        const uint32_t* flg = flags + lane;

        // dummy burn state (register-only; keeps matrix pipe busy during polls)
        short8 bz = {0, 0, 0, 0, 0, 0, 0, 0};
        f32x4 bd0 = fzero(), bd1 = fzero();

        for (int t = 0; t < 256; ++t) {
            if (t > 0) {
                while (true) {
                    const uint32_t v = __hip_atomic_load(flg, __ATOMIC_RELAXED,
                                                         __HIP_MEMORY_SCOPE_AGENT);
                    if (__all((int)(v >= (uint32_t)t))) break;
#pragma unroll
                    for (int i = 0; i < 4; ++i) {
                        bd0 = __builtin_amdgcn_mfma_f32_16x16x32_bf16(bz, bz, bd0, 0, 0, 0);
                        bd1 = __builtin_amdgcn_mfma_f32_16x16x32_bf16(bz, bz, bd1, 0, 0, 0);
                    }
                }
                __builtin_amdgcn_sched_barrier(0);
            }

            const uint32_t* hbase = (t == 0)
                ? (zeroh + (size_t)c * 512)
                : (hsP + ((size_t)(t - 1) * 16 + c) * 512);

            f32x4 acc[2][2];
#pragma unroll
            for (int nt = 0; nt < 2; ++nt) { acc[nt][0] = fzero(); acc[nt][1] = fzero(); }

#pragma unroll
            for (int q = 0; q < 16; ++q) {
                const int kb = q * 32 + qtr * 8;
                const unsigned long long* hb64 = (const unsigned long long*)(hbase + kb);
                unsigned long long d[4];
#pragma unroll
                for (int i = 0; i < 4; ++i)
                    d[i] = __hip_atomic_load(hb64 + i, __ATOMIC_RELAXED,
                                             __HIP_MEMORY_SCOPE_AGENT);
                short8 ahi, alo;
#pragma unroll
                for (int i = 0; i < 4; ++i) {
                    const uint32_t wlo32 = (uint32_t)d[i];
                    const uint32_t whi32 = (uint32_t)(d[i] >> 32);
                    ahi[2 * i]     = (short)(wlo32 >> 16); alo[2 * i]     = (short)(wlo32 & 0xffffu);
                    ahi[2 * i + 1] = (short)(whi32 >> 16); alo[2 * i + 1] = (short)(whi32 & 0xffffu);
                }
#pragma unroll
                for (int nt = 0; nt < 2; ++nt) {
                    const int l = nt * 16 + c;
                    const short8 bhi = *(const short8*)((const char*)whh + l * 1024 +
                                                        (((q * 4 + qtr) ^ (l & 7)) << 4));
                    const short8 blo = WLO8[(((size_t)wg * 2 + nt) * 16 + q) * 64 + lane];
                    f32x4 a = acc[nt][q & 1];
                    a = __builtin_amdgcn_mfma_f32_16x16x32_bf16(ahi, bhi, a, 0, 0, 0);
                    a = __builtin_amdgcn_mfma_f32_16x16x32_bf16(ahi, blo, a, 0, 0, 0);
                    a = __builtin_amdgcn_mfma_f32_16x16x32_bf16(alo, bhi, a, 0, 0, 0);
                    acc[nt][q & 1] = a;
                }
            }

#pragma unroll
            for (int nt = 0; nt < 2; ++nt) {
                f32x4 z4 = acc[nt][0] + acc[nt][1];
#pragma unroll
                for (int r = 0; r < 4; ++r) z4[r] += xzv[nt][r] + bh_v[nt];
#pragma unroll
                for (int r = 0; r < 4; ++r) {
                    const int sb = (lane & 0x33);
                    const float zi = __shfl(z4[r], sb);
                    const float zf = __shfl(z4[r], sb | 4);
                    const float zg = __shfl(z4[r], sb | 8);
                    const float zo = __shfl(z4[r], sb | 12);
                    const float iv = sigm(zi), fv = sigm(zf);
                    const float gv = tanh_fast(zg), ov = sigm(zo);
                    const float cv = fv * cst[nt][r] + iv * gv;
                    cst[nt][r] = cv;
                    const float hv = ov * tanh_fast(cv);
                    if ((c >> 2) == 0) {  // one owner lane per (b, j)
                        const unsigned short hi = f2bf(hv);
                        const unsigned short lo = f2bf(hv - bf2f(hi));
                        const uint32_t packed = (((uint32_t)hi) << 16) | lo;
                        __hip_atomic_store(
                            &hsP[((size_t)t * 16 + qtr * 4 + r) * 512 + wg * 8 + nt * 4 + c],
                            packed, __ATOMIC_RELAXED, __HIP_MEMORY_SCOPE_AGENT);
                    }
                }
            }

            // own h-stores at coherence point before flag becomes visible
            asm volatile("s_waitcnt vmcnt(0)" ::: "memory");
            if (lane == 0)
                __hip_atomic_store(&flags[wg], (uint32_t)(t + 1), __ATOMIC_RELAXED,
                                   __HIP_MEMORY_SCOPE_AGENT);

            if (t < 255) {
#pragma unroll
                for (int nt = 0; nt < 2; ++nt)
#pragma unroll
                    for (int r = 0; r < 4; ++r)
                        xzv[nt][r] = bf2f(xzH[((size_t)(t + 1) * 16 + qtr * 4 + r) * 2048 + gc[nt]]);
            }
        }
        // keep burn accumulators live (rule 17)
        asm volatile("" :: "v"(bd0), "v"(bd1));
    } else {
        // ========== CONSUMER: 192 blocks, s0-outer / v-inner, burn-poll ==========
        unsigned short (*Ah)[64] = (unsigned short(*)[64])(smem);
        unsigned short (*Al)[64] = (unsigned short(*)[64])(smem + 16384);
        unsigned short (*Bh)[64] = (unsigned short(*)[64])(smem + 32768);
        unsigned short (*Bl)[64] = (unsigned short(*)[64])(smem + 49152);

        const int cid = blockIdx.x - 64;   // 0..191
        const int tid = threadIdx.x;
        const int lane = tid & 63;
        const int wv = tid >> 6;
        const int wr = wv >> 1, wc = wv & 1;
        const int srow = tid >> 1, shalf = tid & 1;

        // dummy burn state (register-only)
        short8 bz = {0, 0, 0, 0, 0, 0, 0, 0};
        f32x4 bd0 = fzero(), bd1 = fzero(), bd2 = fzero(), bd3 = fzero();

        for (int s0 = 0; s0 < 32; ++s0) {
            const unsigned need = (unsigned)(s0 * 8 + 8);
            while (true) {
                const unsigned f = __hip_atomic_load(&flags[lane], __ATOMIC_RELAXED,
                                                     __HIP_MEMORY_SCOPE_AGENT);
                if (__all((int)(f >= need))) break;
                // burn the matrix pipe: 32 indep-chain dummy MFMAs (register-only)
#pragma unroll
                for (int i = 0; i < 8; ++i) {
                    bd0 = __builtin_amdgcn_mfma_f32_16x16x32_bf16(bz, bz, bd0, 0, 0, 0);
                    bd1 = __builtin_amdgcn_mfma_f32_16x16x32_bf16(bz, bz, bd1, 0, 0, 0);
                    bd2 = __builtin_amdgcn_mfma_f32_16x16x32_bf16(bz, bz, bd2, 0, 0, 0);
                    bd3 = __builtin_amdgcn_mfma_f32_16x16x32_bf16(bz, bz, bd3, 0, 0, 0);
                }
            }

            for (int vi = 0; vi < 3; ++vi) {
                const int v = cid + vi * 192;
                if (v >= 393) break;

                f32x4 acc[4][4];
#pragma unroll
                for (int i = 0; i < 4; ++i)
#pragma unroll
                    for (int j = 0; j < 4; ++j) acc[i][j] = fzero();

                for (int kb = 0; kb < 8; ++kb) {
                    __syncthreads();
                    const uint32_t* sa = hsP + (size_t)(s0 * 128 + srow) * 512 + kb * 64 + shalf * 32;
                    const uint32_t* sbp = WoTP + (size_t)(v * 128 + srow) * 512 + kb * 64 + shalf * 32;
                    u32x4 av[8], bv[8];
#pragma unroll
                    for (int g = 0; g < 4; ++g) {
                        aload16(av[2 * g], sa + g * 8);
                        aload16(av[2 * g + 1], sa + g * 8 + 4);
                    }
#pragma unroll
                    for (int g = 0; g < 4; ++g) {
                        bv[2 * g]     = *(const u32x4*)(sbp + g * 8);
                        bv[2 * g + 1] = *(const u32x4*)(sbp + g * 8 + 4);
                    }
                    asm volatile("s_waitcnt vmcnt(0)" ::: "memory");
                    __builtin_amdgcn_sched_barrier(0);
#pragma unroll
                    for (int g = 0; g < 4; ++g) {
                        short8 hi, lo;
#pragma unroll
                        for (int i = 0; i < 4; ++i) {
                            hi[i]     = (short)(av[2 * g][i] >> 16);
                            lo[i]     = (short)(av[2 * g][i] & 0xffffu);
                            hi[4 + i] = (short)(av[2 * g + 1][i] >> 16);
                            lo[4 + i] = (short)(av[2 * g + 1][i] & 0xffffu);
                        }
                        const int sw = ((shalf * 4 + g) ^ (srow & 7)) << 4;
                        *(short8*)((char*)Ah + srow * 128 + sw) = hi;
                        *(short8*)((char*)Al + srow * 128 + sw) = lo;
                    }
#pragma unroll
                    for (int g = 0; g < 4; ++g) {
                        short8 hi, lo;
#pragma unroll
                        for (int i = 0; i < 4; ++i) {
                            hi[i]     = (short)(bv[2 * g][i] >> 16);
                            lo[i]     = (short)(bv[2 * g][i] & 0xffffu);
                            hi[4 + i] = (short)(bv[2 * g + 1][i] >> 16);
                            lo[4 + i] = (short)(bv[2 * g + 1][i] & 0xffffu);
                        }
                        const int sw = ((shalf * 4 + g) ^ (srow & 7)) << 4;
                        *(short8*)((char*)Bh + srow * 128 + sw) = hi;
                        *(short8*)((char*)Bl + srow * 128 + sw) = lo;
                    }
                    __syncthreads();

#pragma unroll
                    for (int q = 0; q < 2; ++q) {
                        short8 afh[4], afl[4], bfh[4], bfl[4];
#pragma unroll
                        for (int mi = 0; mi < 4; ++mi) {
                            const int r = wr * 64 + mi * 16 + (lane & 15);
                            const int sw = ((q * 4 + (lane >> 4)) ^ (r & 7)) << 4;
                            afh[mi] = *(const short8*)((const char*)Ah + r * 128 + sw);
                            afl[mi] = *(const short8*)((const char*)Al + r * 128 + sw);
                        }
#pragma unroll
                        for (int nj = 0; nj < 4; ++nj) {
                            const int r = wc * 64 + nj * 16 + (lane & 15);
                            const int sw = ((q * 4 + (lane >> 4)) ^ (r & 7)) << 4;
                            bfh[nj] = *(const short8*)((const char*)Bh + r * 128 + sw);
                            bfl[nj] = *(const short8*)((const char*)Bl + r * 128 + sw);
                        }
#pragma unroll
                        for (int mi = 0; mi < 4; ++mi)
#pragma unroll
                            for (int nj = 0; nj < 4; ++nj) {
                                f32x4 a = acc[mi][nj];
                                a = __builtin_amdgcn_mfma_f32_16x16x32_bf16(afh[mi], bfh[nj], a, 0, 0, 0);
                                a = __builtin_amdgcn_mfma_f32_16x16x32_bf16(afh[mi], bfl[nj], a, 0, 0, 0);
                                a = __builtin_amdgcn_mfma_f32_16x16x32_bf16(afl[mi], bfh[nj], a, 0, 0, 0);
                                acc[mi][nj] = a;
                            }
                    }
                }

#pragma unroll
                for (int nj = 0; nj < 4; ++nj) {
                    const int colg = v * 128 + wc * 64 + nj * 16 + (lane & 15);
                    if (colg < 50257) {
                        const float bov = bo[colg];
#pragma unroll
                        for (int mi = 0; mi < 4; ++mi)
#pragma unroll
                            for (int r = 0; r < 4; ++r) {
                                const int tr = wr * 64 + mi * 16 + (lane >> 4) * 4 + r;
                                const int ss = s0 * 8 + (tr >> 4);
                                const int bb = tr & 15;
                                out[((size_t)bb * 256 + ss) * 50257 + colg] = acc[mi][nj][r] + bov;
                            }
                    }
                }
            }
        }
        // keep burn accumulators live (rule 17)
        asm volatile("" :: "v"(bd0), "v"(bd1), "v"(bd2), "v"(bd3));
    }
}

// ---------------- launch ----------------------------------------------------------------
// Workspace layout (total ~130 MB <= proven-safe 147 MB):
#define XZH_OFF  0ull           // 256*16*2048*2  = 16,777,216  (bf16 xz)
#define HSP_OFF  16777216ull    // 256*16*512*4   =  8,388,608  (packed u32 h, t-major)
#define ZERO_OFF 25165824ull    // 16*512*4       =     32,768
#define FLG_OFF  25198592ull    // 64*4 = 256
#define WLO_OFF  25198848ull    // 64*2*16*64*16  =  2,097,152
#define WOT_OFF  27296000ull    // 50304*512*4    = 103,022,592

extern "C" void kernel_launch(void* const* d_in, const int* in_sizes, int n_in,
                              void* d_out, int out_size, void* d_ws, size_t ws_size,
                              hipStream_t stream) {
    (void)in_sizes; (void)n_in; (void)out_size; (void)ws_size;
    const int*   idx = (const int*)  d_in[0];
    const float* E   = (const float*)d_in[1];
    const float* Wi  = (const float*)d_in[2];
    const float* Wh  = (const float*)d_in[3];
    const float* bh  = (const float*)d_in[4];
    const float* Wo  = (const float*)d_in[5];
    const float* bo  = (const float*)d_in[6];
    float* out = (float*)d_out;
    char* ws = (char*)d_ws;

    unsigned short* xzH   = (unsigned short*)(ws + XZH_OFF);
    uint32_t*       hsP   = (uint32_t*)      (ws + HSP_OFF);
    uint32_t*       zeroh = (uint32_t*)      (ws + ZERO_OFF);
    uint32_t*       flags = (uint32_t*)      (ws + FLG_OFF);
    uint32_t*       WLO   = (uint32_t*)      (ws + WLO_OFF);
    uint32_t*       WoTP  = (uint32_t*)      (ws + WOT_OFF);

    // zero h(-1) block + flags each call (contiguous region; no cross-replay state)
    hipMemsetAsync(ws + ZERO_OFF, 0, 33024, stream);

    hipLaunchKernelGGL(k0_wot,   dim3(25152), dim3(256), 0, stream, Wo, WoTP);
    hipLaunchKernelGGL(k0b_whlo, dim3(512),   dim3(256), 0, stream, Wh, WLO);
    hipLaunchKernelGGL(k1_xz,    dim3(256),   dim3(256), 0, stream, idx, E, Wi, xzH);
    hipLaunchKernelGGL(k23,      dim3(256),   dim3(256), 0, stream,
                       Wh, bh, xzH, (const short8*)WLO, hsP, zeroh, flags, WoTP, bo, out);
}

// Round 8
// 3346.594 us; speedup vs baseline: 1.2509x; 1.1442x over previous
//
#include <hip/hip_runtime.h>
#include <cstdint>

// LSTM LM: logits = LSTM(E[idx] @ Wi) @ Wo + bo
// B=16, S=256, D=256, H=512, 4H=2048, V=50257 (padded to 50304 = 393*128)
//
// Round-8: consolidated producers + epoch-counter barrier (deadlock-proof).
//  - blocks 0..15  : producers, 4 waves each = 64 virtual producers (vp),
//    byte-identical per-wave math to the validated r2/r4/r6 pipeline.
//    128KB LDS = 4 Wh-hi slices. Per step: syncthreads (intra-block), then
//    ONE atomicAdd on a global epoch counter per block; wave0 polls the
//    counter, waves 1-3 gate on an LDS mirror. 16 RMWs + 16 pollers total
//    (vs r6's 64x64-lane scatter polls) -> less MALL hotspotting.
//  - blocks 16..255: 240 consumers (r6 GEMM unchanged), gated on a separate
//    mirror word epC written by block 0 (zero consumer load on the RMW line).
//  Liveness: roles from blockIdx only; producers dispatched first; frontier
//  never waits on consumers; consumers see epC==256 even if scheduled late.
//  (r7 post-mortem: XCD-placement-dependent roles deadlocked.)

typedef __attribute__((ext_vector_type(8))) short short8;
typedef __attribute__((ext_vector_type(4))) float f32x4;
typedef __attribute__((ext_vector_type(4))) unsigned int u32x4;
typedef __attribute__((ext_vector_type(4))) unsigned short ush4;

#define DEVFN static __device__ __forceinline__

DEVFN unsigned short f2bf(float f) {
    unsigned int u = __float_as_uint(f);
    return (unsigned short)((u + 0x7FFFu + ((u >> 16) & 1u)) >> 16);  // RNE
}
DEVFN float bf2f(unsigned short h) { return __uint_as_float(((unsigned int)h) << 16); }
DEVFN float sigm(float x) { return 1.0f / (1.0f + __expf(-x)); }
DEVFN float tanh_fast(float x) {
    float e = __expf(-2.0f * fabsf(x));
    float t = (1.0f - e) / (1.0f + e);
    return copysignf(t, x);
}
DEVFN f32x4 fzero() { f32x4 v = {0.f, 0.f, 0.f, 0.f}; return v; }

// MALL-coherent (L1+L2 bypass) scalar flag load/store.
DEVFN uint32_t ld_flag_mall(const uint32_t* p) {
    uint32_t v;
    asm volatile("global_load_dword %0, %1, off sc0 sc1\n\ts_waitcnt vmcnt(0)"
                 : "=v"(v) : "v"(p) : "memory");
    return v;
}
DEVFN void st_flag_mall(uint32_t* p, uint32_t v) {
    asm volatile("global_store_dword %0, %1, off sc0 sc1" :: "v"(p), "v"(v) : "memory");
}
// 16B MALL-coherent load (no embedded wait; batch + vmcnt(0) at call site).
DEVFN void aload16(u32x4& d, const void* p) {
    asm volatile("global_load_dwordx4 %0, %1, off sc0 sc1" : "=v"(d) : "v"(p));
}

// ---------------- k0: transpose + split Wo -> WoTP[50304][512] packed u32 ----------------
__global__ __launch_bounds__(256) void k0_wot(const float* __restrict__ Wo,
                                              uint32_t* __restrict__ WoTP) {
    __shared__ float tile[32][33];
    const int bx = blockIdx.x;
    const int cb = bx >> 4;
    const int kb = bx & 15;
    const int c0 = cb * 32, k0 = kb * 32;
    const int j = threadIdx.x & 31;
    const int i0 = threadIdx.x >> 5;
    for (int ii = i0; ii < 32; ii += 8) {
        const int c = c0 + j;
        tile[ii][j] = (c < 50257) ? Wo[(size_t)(k0 + ii) * 50257 + c] : 0.0f;
    }
    __syncthreads();
    for (int ii = i0; ii < 32; ii += 8) {
        const float v = tile[j][ii];
        const unsigned short hi = f2bf(v);
        const unsigned short lo = f2bf(v - bf2f(hi));
        WoTP[(size_t)(c0 + ii) * 512 + k0 + j] = (((unsigned int)hi) << 16) | lo;
    }
}

// ---------------- k0b: Wh bf16-lo B-fragments: [vp][nt][q][lane] 16B each ----------------
__global__ __launch_bounds__(256) void k0b_whlo(const float* __restrict__ Wh,
                                                uint32_t* __restrict__ WLO) {
    const int tid = blockIdx.x * 256 + threadIdx.x;
    const int lane = tid & 63;
    const int q    = (tid >> 6) & 15;
    const int nt   = (tid >> 10) & 1;
    const int vp   = tid >> 11;          // virtual producer 0..63 (8 hidden units each)
    const int cc   = lane & 15;
    const int gcol = (cc >> 2) * 512 + vp * 8 + nt * 4 + (cc & 3);
    const int kbase = q * 32 + (lane >> 4) * 8;
    u32x4 o;
#pragma unroll
    for (int p = 0; p < 4; ++p) {
        unsigned int pair = 0;
#pragma unroll
        for (int e = 0; e < 2; ++e) {
            const int k = kbase + p * 2 + e;
            const float w = Wh[(size_t)k * 2048 + gcol];
            const unsigned short hi = f2bf(w);
            const unsigned short lo = f2bf(w - bf2f(hi));
            pair |= ((unsigned int)lo) << (e * 16);
        }
        o[p] = pair;
    }
    *(u32x4*)(WLO + (size_t)tid * 4) = o;
}

// ---------------- k1: xzH[s][b][g] = bf16( sum_d E[idx[b,s],d] * Wi[d,g] ) ---------------
__global__ __launch_bounds__(256) void k1_xz(const int* __restrict__ idx,
                                             const float* __restrict__ E,
                                             const float* __restrict__ Wi,
                                             unsigned short* __restrict__ xzH) {
    __shared__ float xs[16][256];
    const int s = blockIdx.x;
    const int t = threadIdx.x;
#pragma unroll
    for (int b = 0; b < 16; ++b) {
        const int row = idx[b * 256 + s];
        xs[b][t] = E[(size_t)row * 256 + t];
    }
    __syncthreads();
    for (int half = 0; half < 2; ++half) {
        const int g0 = half * 1024 + t * 4;
        f32x4 acc[16];
#pragma unroll
        for (int b = 0; b < 16; ++b) acc[b] = fzero();
        for (int d = 0; d < 256; ++d) {
            const f32x4 w = *(const f32x4*)&Wi[(size_t)d * 2048 + g0];
#pragma unroll
            for (int b = 0; b < 16; ++b) {
                const float xv = xs[b][d];
                acc[b] += xv * w;
            }
        }
#pragma unroll
        for (int b = 0; b < 16; ++b) {
            ush4 o;
#pragma unroll
            for (int jj = 0; jj < 4; ++jj) o[jj] = f2bf(acc[b][jj]);
            *(ush4*)&xzH[((size_t)s * 16 + b) * 2048 + g0] = o;
        }
    }
}

// ---------------- k23: fused recurrence (16 blocks) + consumer GEMM (240 blocks) ---------
__global__ __launch_bounds__(256, 1) void k23(const float* __restrict__ Wh,
                                              const float* __restrict__ bh,
                                              const unsigned short* __restrict__ xzH,
                                              const short8* __restrict__ WLO8,
                                              uint32_t* __restrict__ hsP,
                                              const uint32_t* __restrict__ zeroh,
                                              uint32_t* __restrict__ ep,    // epoch RMW ctr
                                              uint32_t* __restrict__ epC,   // consumer mirror
                                              const uint32_t* __restrict__ WoTP,
                                              const float* __restrict__ bo,
                                              float* __restrict__ out) {
    __shared__ __align__(16) char smem[131072];   // 128KB -> 1 block/CU
    __shared__ unsigned int sEp;

    const int tid = threadIdx.x;

    if (blockIdx.x < 16) {
        // ================= PRODUCER block: 4 frontier waves (vp = blk*4 + w) =============
        const int blk = blockIdx.x;

        // stage 4 Wh-hi slices (32KB each), r2's mapping per slice
        for (int vs = 0; vs < 4; ++vs) {
            const int vp_s = blk * 4 + vs;
            const int l = tid >> 3, seg = tid & 7;
            const int cc = l & 15, nt0 = l >> 4;
            const int gcol = (cc >> 2) * 512 + vp_s * 8 + nt0 * 4 + (cc & 3);
            for (int k8 = seg * 64; k8 < seg * 64 + 64; k8 += 8) {
                short8 v;
#pragma unroll
                for (int i = 0; i < 8; ++i)
                    v[i] = (short)f2bf(Wh[(size_t)(k8 + i) * 2048 + gcol]);
                const int slot = (k8 >> 3) ^ (l & 7);
                *(short8*)(smem + vs * 32768 + l * 1024 + slot * 16) = v;
            }
        }
        if (tid == 0) sEp = 0;
        __syncthreads();

        const int w = tid >> 6;
        const int lane = tid & 63;
        const int vp = blk * 4 + w;
        unsigned short* whhW = (unsigned short*)(smem + w * 32768);
        const int c = lane & 15;
        const int qtr = lane >> 4;

        int gc[2];
        float bh_v[2];
#pragma unroll
        for (int nt = 0; nt < 2; ++nt) {
            gc[nt] = (c >> 2) * 512 + vp * 8 + nt * 4 + (c & 3);
            bh_v[nt] = bh[gc[nt]];
        }
        float cst[2][4];
#pragma unroll
        for (int nt = 0; nt < 2; ++nt)
#pragma unroll
            for (int r = 0; r < 4; ++r) cst[nt][r] = 0.0f;

        float xzv[2][4];
#pragma unroll
        for (int nt = 0; nt < 2; ++nt)
#pragma unroll
            for (int r = 0; r < 4; ++r)
                xzv[nt][r] = bf2f(xzH[(size_t)(qtr * 4 + r) * 2048 + gc[nt]]);

        short8 bz = {0, 0, 0, 0, 0, 0, 0, 0};
        f32x4 bd0 = fzero(), bd1 = fzero();

        for (int t = 0; t < 256; ++t) {
            if (t > 0) {
                const uint32_t tgt = 16u * (uint32_t)t;
                if (w == 0) {
                    while (true) {
                        const uint32_t v = ld_flag_mall(ep);   // uniform addr: 1 req/wave
                        if (v >= tgt) break;
#pragma unroll
                        for (int i = 0; i < 2; ++i) {
                            bd0 = __builtin_amdgcn_mfma_f32_16x16x32_bf16(bz, bz, bd0, 0, 0, 0);
                            bd1 = __builtin_amdgcn_mfma_f32_16x16x32_bf16(bz, bz, bd1, 0, 0, 0);
                        }
                    }
                    if (lane == 0) {
                        __hip_atomic_store(&sEp, (unsigned)t, __ATOMIC_RELAXED,
                                           __HIP_MEMORY_SCOPE_WORKGROUP);
                        if (blk == 0) st_flag_mall(epC, (uint32_t)t);  // consumer mirror
                    }
                } else {
                    while (__hip_atomic_load(&sEp, __ATOMIC_RELAXED,
                                             __HIP_MEMORY_SCOPE_WORKGROUP) < (unsigned)t) {}
                }
                __builtin_amdgcn_sched_barrier(0);
            }

            const uint32_t* hbase = (t == 0)
                ? (zeroh + (size_t)c * 512)
                : (hsP + ((size_t)(t - 1) * 16 + c) * 512);

            f32x4 acc[2][2];
#pragma unroll
            for (int nt = 0; nt < 2; ++nt) { acc[nt][0] = fzero(); acc[nt][1] = fzero(); }

#pragma unroll
            for (int q = 0; q < 16; ++q) {
                const int kb = q * 32 + qtr * 8;
                const unsigned long long* hb64 = (const unsigned long long*)(hbase + kb);
                unsigned long long d[4];
#pragma unroll
                for (int i = 0; i < 4; ++i)
                    d[i] = __hip_atomic_load(hb64 + i, __ATOMIC_RELAXED,
                                             __HIP_MEMORY_SCOPE_AGENT);
                short8 ahi, alo;
#pragma unroll
                for (int i = 0; i < 4; ++i) {
                    const uint32_t wlo32 = (uint32_t)d[i];
                    const uint32_t whi32 = (uint32_t)(d[i] >> 32);
                    ahi[2 * i]     = (short)(wlo32 >> 16); alo[2 * i]     = (short)(wlo32 & 0xffffu);
                    ahi[2 * i + 1] = (short)(whi32 >> 16); alo[2 * i + 1] = (short)(whi32 & 0xffffu);
                }
#pragma unroll
                for (int nt = 0; nt < 2; ++nt) {
                    const int l = nt * 16 + c;
                    const short8 bhi = *(const short8*)((const char*)whhW + l * 1024 +
                                                        (((q * 4 + qtr) ^ (l & 7)) << 4));
                    const short8 blo = WLO8[(((size_t)vp * 2 + nt) * 16 + q) * 64 + lane];
                    f32x4 a = acc[nt][q & 1];
                    a = __builtin_amdgcn_mfma_f32_16x16x32_bf16(ahi, bhi, a, 0, 0, 0);
                    a = __builtin_amdgcn_mfma_f32_16x16x32_bf16(ahi, blo, a, 0, 0, 0);
                    a = __builtin_amdgcn_mfma_f32_16x16x32_bf16(alo, bhi, a, 0, 0, 0);
                    acc[nt][q & 1] = a;
                }
            }

#pragma unroll
            for (int nt = 0; nt < 2; ++nt) {
                f32x4 z4 = acc[nt][0] + acc[nt][1];
#pragma unroll
                for (int r = 0; r < 4; ++r) z4[r] += xzv[nt][r] + bh_v[nt];
#pragma unroll
                for (int r = 0; r < 4; ++r) {
                    const int sb = (lane & 0x33);
                    const float zi = __shfl(z4[r], sb);
                    const float zf = __shfl(z4[r], sb | 4);
                    const float zg = __shfl(z4[r], sb | 8);
                    const float zo = __shfl(z4[r], sb | 12);
                    const float iv = sigm(zi), fv = sigm(zf);
                    const float gv = tanh_fast(zg), ov = sigm(zo);
                    const float cv = fv * cst[nt][r] + iv * gv;
                    cst[nt][r] = cv;
                    const float hv = ov * tanh_fast(cv);
                    if ((c >> 2) == 0) {   // one owner lane per (b, j)
                        const unsigned short hi = f2bf(hv);
                        const unsigned short lo = f2bf(hv - bf2f(hi));
                        const uint32_t packed = (((uint32_t)hi) << 16) | lo;
                        __hip_atomic_store(
                            &hsP[((size_t)t * 16 + qtr * 4 + r) * 512 + vp * 8 + nt * 4 + c],
                            packed, __ATOMIC_RELAXED, __HIP_MEMORY_SCOPE_AGENT);
                    }
                }
            }

            // all 4 waves: own h-stores ACKed, then one RMW per block
            asm volatile("s_waitcnt vmcnt(0)" ::: "memory");
            __syncthreads();
            if (tid == 0)
                __hip_atomic_fetch_add(ep, 1u, __ATOMIC_RELAXED, __HIP_MEMORY_SCOPE_AGENT);

            if (t < 255) {
#pragma unroll
                for (int nt = 0; nt < 2; ++nt)
#pragma unroll
                    for (int r = 0; r < 4; ++r)
                        xzv[nt][r] = bf2f(xzH[((size_t)(t + 1) * 16 + qtr * 4 + r) * 2048 + gc[nt]]);
            }
        }

        // epilogue: block 0 publishes final epoch for consumers (s0=31 needs 256)
        if (blk == 0 && tid == 0) {
            while (ld_flag_mall(ep) < 4096u) {}
            st_flag_mall(epC, 256u);
        }
        asm volatile("" :: "v"(bd0), "v"(bd1));
    } else {
        // ================= CONSUMER (240 blocks): s0-outer / v-inner =====================
        unsigned short (*Ah)[64] = (unsigned short(*)[64])(smem);
        unsigned short (*Al)[64] = (unsigned short(*)[64])(smem + 16384);
        unsigned short (*Bh)[64] = (unsigned short(*)[64])(smem + 32768);
        unsigned short (*Bl)[64] = (unsigned short(*)[64])(smem + 49152);

        const int cid = blockIdx.x - 16;   // 0..239
        const int lane = tid & 63;
        const int wv = tid >> 6;
        const int wr = wv >> 1, wc = wv & 1;
        const int srow = tid >> 1, shalf = tid & 1;

        short8 bz = {0, 0, 0, 0, 0, 0, 0, 0};
        f32x4 bd0 = fzero(), bd1 = fzero(), bd2 = fzero(), bd3 = fzero();

        for (int s0 = 0; s0 < 32; ++s0) {
            const unsigned need = (unsigned)(s0 * 8 + 8);   // steps done required
            while (true) {
                const uint32_t f = ld_flag_mall(epC);       // uniform addr: 1 req/wave
                if (f >= need) break;
#pragma unroll
                for (int i = 0; i < 8; ++i) {
                    bd0 = __builtin_amdgcn_mfma_f32_16x16x32_bf16(bz, bz, bd0, 0, 0, 0);
                    bd1 = __builtin_amdgcn_mfma_f32_16x16x32_bf16(bz, bz, bd1, 0, 0, 0);
                    bd2 = __builtin_amdgcn_mfma_f32_16x16x32_bf16(bz, bz, bd2, 0, 0, 0);
                    bd3 = __builtin_amdgcn_mfma_f32_16x16x32_bf16(bz, bz, bd3, 0, 0, 0);
                }
            }

            for (int vi = 0; vi < 2; ++vi) {
                const int v = cid + vi * 240;
                if (v >= 393) break;

                f32x4 acc[4][4];
#pragma unroll
                for (int i = 0; i < 4; ++i)
#pragma unroll
                    for (int j = 0; j < 4; ++j) acc[i][j] = fzero();

                for (int kb = 0; kb < 8; ++kb) {
                    __syncthreads();
                    const uint32_t* sa = hsP + (size_t)(s0 * 128 + srow) * 512 + kb * 64 + shalf * 32;
                    const uint32_t* sbp = WoTP + (size_t)(v * 128 + srow) * 512 + kb * 64 + shalf * 32;
                    u32x4 av[8], bv[8];
#pragma unroll
                    for (int g = 0; g < 4; ++g) {
                        aload16(av[2 * g], sa + g * 8);
                        aload16(av[2 * g + 1], sa + g * 8 + 4);
                    }
#pragma unroll
                    for (int g = 0; g < 4; ++g) {
                        bv[2 * g]     = *(const u32x4*)(sbp + g * 8);
                        bv[2 * g + 1] = *(const u32x4*)(sbp + g * 8 + 4);
                    }
                    asm volatile("s_waitcnt vmcnt(0)" ::: "memory");
                    __builtin_amdgcn_sched_barrier(0);
#pragma unroll
                    for (int g = 0; g < 4; ++g) {
                        short8 hi, lo;
#pragma unroll
                        for (int i = 0; i < 4; ++i) {
                            hi[i]     = (short)(av[2 * g][i] >> 16);
                            lo[i]     = (short)(av[2 * g][i] & 0xffffu);
                            hi[4 + i] = (short)(av[2 * g + 1][i] >> 16);
                            lo[4 + i] = (short)(av[2 * g + 1][i] & 0xffffu);
                        }
                        const int sw = ((shalf * 4 + g) ^ (srow & 7)) << 4;
                        *(short8*)((char*)Ah + srow * 128 + sw) = hi;
                        *(short8*)((char*)Al + srow * 128 + sw) = lo;
                    }
#pragma unroll
                    for (int g = 0; g < 4; ++g) {
                        short8 hi, lo;
#pragma unroll
                        for (int i = 0; i < 4; ++i) {
                            hi[i]     = (short)(bv[2 * g][i] >> 16);
                            lo[i]     = (short)(bv[2 * g][i] & 0xffffu);
                            hi[4 + i] = (short)(bv[2 * g + 1][i] >> 16);
                            lo[4 + i] = (short)(bv[2 * g + 1][i] & 0xffffu);
                        }
                        const int sw = ((shalf * 4 + g) ^ (srow & 7)) << 4;
                        *(short8*)((char*)Bh + srow * 128 + sw) = hi;
                        *(short8*)((char*)Bl + srow * 128 + sw) = lo;
                    }
                    __syncthreads();

#pragma unroll
                    for (int q = 0; q < 2; ++q) {
                        short8 afh[4], afl[4], bfh[4], bfl[4];
#pragma unroll
                        for (int mi = 0; mi < 4; ++mi) {
                            const int r = wr * 64 + mi * 16 + (lane & 15);
                            const int sw = ((q * 4 + (lane >> 4)) ^ (r & 7)) << 4;
                            afh[mi] = *(const short8*)((const char*)Ah + r * 128 + sw);
                            afl[mi] = *(const short8*)((const char*)Al + r * 128 + sw);
                        }
#pragma unroll
                        for (int nj = 0; nj < 4; ++nj) {
                            const int r = wc * 64 + nj * 16 + (lane & 15);
                            const int sw = ((q * 4 + (lane >> 4)) ^ (r & 7)) << 4;
                            bfh[nj] = *(const short8*)((const char*)Bh + r * 128 + sw);
                            bfl[nj] = *(const short8*)((const char*)Bl + r * 128 + sw);
                        }
#pragma unroll
                        for (int mi = 0; mi < 4; ++mi)
#pragma unroll
                            for (int nj = 0; nj < 4; ++nj) {
                                f32x4 a = acc[mi][nj];
                                a = __builtin_amdgcn_mfma_f32_16x16x32_bf16(afh[mi], bfh[nj], a, 0, 0, 0);
                                a = __builtin_amdgcn_mfma_f32_16x16x32_bf16(afh[mi], bfl[nj], a, 0, 0, 0);
                                a = __builtin_amdgcn_mfma_f32_16x16x32_bf16(afl[mi], bfh[nj], a, 0, 0, 0);
                                acc[mi][nj] = a;
                            }
                    }
                }

#pragma unroll
                for (int nj = 0; nj < 4; ++nj) {
                    const int colg = v * 128 + wc * 64 + nj * 16 + (lane & 15);
                    if (colg < 50257) {
                        const float bov = bo[colg];
#pragma unroll
                        for (int mi = 0; mi < 4; ++mi)
#pragma unroll
                            for (int r = 0; r < 4; ++r) {
                                const int tr = wr * 64 + mi * 16 + (lane >> 4) * 4 + r;
                                const int ss = s0 * 8 + (tr >> 4);
                                const int bb = tr & 15;
                                out[((size_t)bb * 256 + ss) * 50257 + colg] = acc[mi][nj][r] + bov;
                            }
                    }
                }
            }
        }
        asm volatile("" :: "v"(bd0), "v"(bd1), "v"(bd2), "v"(bd3));
    }
}

// ---------------- launch ----------------------------------------------------------------
// Workspace (total ~130 MB <= proven-safe 147 MB):
#define XZH_OFF   0ull          // 256*16*2048*2  = 16,777,216  (bf16 xz)
#define HSP_OFF   16777216ull   // 256*16*512*4   =  8,388,608  (packed u32 h, t-major)
#define ZEROH_OFF 25165824ull   // 16*512*4       = 32,768
#define FLG_OFF   25198592ull   // 256 bytes: ep @ +0, epC @ +128 (separate lines)
#define WLO_OFF   25198848ull   // 64*2*16*64*16  =  2,097,152
#define WOT_OFF   27296000ull   // 50304*512*4    = 103,022,592

extern "C" void kernel_launch(void* const* d_in, const int* in_sizes, int n_in,
                              void* d_out, int out_size, void* d_ws, size_t ws_size,
                              hipStream_t stream) {
    (void)in_sizes; (void)n_in; (void)out_size; (void)ws_size;
    const int*   idx = (const int*)  d_in[0];
    const float* E   = (const float*)d_in[1];
    const float* Wi  = (const float*)d_in[2];
    const float* Wh  = (const float*)d_in[3];
    const float* bh  = (const float*)d_in[4];
    const float* Wo  = (const float*)d_in[5];
    const float* bo  = (const float*)d_in[6];
    float* out = (float*)d_out;
    char* ws = (char*)d_ws;

    unsigned short* xzH   = (unsigned short*)(ws + XZH_OFF);
    uint32_t*       hsP   = (uint32_t*)      (ws + HSP_OFF);
    uint32_t*       zeroh = (uint32_t*)      (ws + ZEROH_OFF);
    uint32_t*       ep    = (uint32_t*)      (ws + FLG_OFF);
    uint32_t*       epC   = (uint32_t*)      (ws + FLG_OFF + 128);
    uint32_t*       WLO   = (uint32_t*)      (ws + WLO_OFF);
    uint32_t*       WoTP  = (uint32_t*)      (ws + WOT_OFF);

    // zero h(-1) block + epoch counters each call (contiguous 33,024 B region)
    hipMemsetAsync(ws + ZEROH_OFF, 0, 33024, stream);

    hipLaunchKernelGGL(k0_wot,   dim3(25152), dim3(256), 0, stream, Wo, WoTP);
    hipLaunchKernelGGL(k0b_whlo, dim3(512),   dim3(256), 0, stream, Wh, WLO);
    hipLaunchKernelGGL(k1_xz,    dim3(256),   dim3(256), 0, stream, idx, E, Wi, xzH);
    hipLaunchKernelGGL(k23,      dim3(256),   dim3(256), 0, stream,
                       Wh, bh, xzH, (const short8*)WLO, hsP, zeroh, ep, epC, WoTP, bo, out);
}